// Round 19
// baseline (302.542 us; speedup 1.0000x reference)
//
#include <hip/hip_runtime.h>
#include <math.h>
#include <stddef.h>

#define CIN 256
#define COUT 256
#define SD 512
#define NB 16
#define KSCALE (1.0f / 48.0f)   // 1/sqrt(256*9)
#define MEPS 1e-8f
#define SRROW 8320               // per-sample row stride (rows of 256 bf16)

typedef __attribute__((ext_vector_type(8))) short short8;
typedef __attribute__((ext_vector_type(4))) float floatx4;
typedef unsigned short ushort;

__device__ inline ushort f2bf(float f) {
    union { float f; unsigned int u; } v; v.f = f;
    unsigned int u = v.u;
    return (ushort)((u + 0x7FFFu + ((u >> 16) & 1u)) >> 16);
}
__device__ inline float bf2f(ushort h) {
    union { unsigned int u; float f; } v; v.u = ((unsigned int)h) << 16;
    return v.f;
}

// async global->LDS, 16B per lane; LDS dest is wave-uniform base + lane*16
__device__ inline void gload16(const ushort* g, ushort* l) {
    __builtin_amdgcn_global_load_lds(
        (const __attribute__((address_space(1))) unsigned int*)g,
        (__attribute__((address_space(3))) unsigned int*)l,
        16, 0, 0);
}

// ---------------- modulation + weight prep, merged single launch (verified r18) -------
__global__ __launch_bounds__(256) void modwprep_k(
    const float* __restrict__ style, const float* __restrict__ weights,
    const float* __restrict__ mod_w, const float* __restrict__ mod_b,
    float* __restrict__ s_all, float* __restrict__ demod_all,
    ushort* __restrict__ Wbf)
{
    int t = threadIdx.x;
    if (blockIdx.x < 64) {
        int layer = blockIdx.x >> 4;
        int b = blockIdx.x & 15;
        __shared__ float st[SD];
        __shared__ float s2[CIN];

        for (int j = t; j < SD; j += 256) st[j] = style[b * SD + j];
        __syncthreads();

        const float* mw = mod_w + ((size_t)layer * CIN + t) * SD;
        float acc = 0.f;
        for (int j = 0; j < SD; ++j) acc += mw[j] * st[j];
        float s = acc + mod_b[layer * CIN + t];
        s_all[((size_t)layer * NB + b) * CIN + t] = s;
        s2[t] = s * s;
        __syncthreads();

        const float* wr = weights + ((size_t)layer * COUT + t) * (CIN * 3);
        float d = 0.f;
        for (int ci = 0; ci < CIN; ++ci) {
            float w0 = wr[ci * 3 + 0], w1 = wr[ci * 3 + 1], w2 = wr[ci * 3 + 2];
            d += (w0 * w0 + w1 * w1 + w2 * w2) * s2[ci];
        }
        demod_all[((size_t)layer * NB + b) * CIN + t] = rsqrtf(KSCALE * KSCALE * d + MEPS);
    } else {
        int lin = blockIdx.x - 64;
        int layer = lin >> 8;
        int idx = (lin & 255) * 256 + t;
        int a = idx >> 8, c = idx & 255;
        ushort* wl = Wbf + (size_t)layer * 196608;
        if (layer == 1) {
            const float* src = weights + ((size_t)1 * 196608) + ((size_t)c * 256 + a) * 3;
            #pragma unroll
            for (int k = 0; k < 3; ++k)
                wl[(size_t)k * 65536 + a * 256 + c] = f2bf(src[k]);
        } else {
            const float* src = weights + ((size_t)layer * 196608) + ((size_t)a * 256 + c) * 3;
            #pragma unroll
            for (int k = 0; k < 3; ++k)
                wl[(size_t)a * 768 + k * 256 + c] = f2bf(src[k]);
        }
    }
}

// ---------------- x prep + T0 guard rows (verified r16-r18) ----------------
__global__ __launch_bounds__(256) void xprep_k(
    const float* __restrict__ x, const float* __restrict__ s0,
    ushort* __restrict__ Tout)
{
    __shared__ ushort lt[64 * 72];
    int l0 = blockIdx.x * 64, ci0 = blockIdx.y * 64;
    int b = blockIdx.z;
    int t = threadIdx.x;
    const float* xb = x + (size_t)b * CIN * 4096;
    const float* sb = s0 + b * CIN;

    for (int idx = t; idx < 64 * 64; idx += 256) {
        int ci = idx >> 6, lc = idx & 63;
        float v = xb[(size_t)(ci0 + ci) * 4096 + l0 + lc] * sb[ci0 + ci];
        lt[lc * 72 + ci] = f2bf(v);
    }
    __syncthreads();
    ushort* ob = Tout + (size_t)b * SRROW * 256;
    for (int idx = t; idx < 64 * 8; idx += 256) {
        int lc = idx >> 3, ch = idx & 7;
        short8 v = *(const short8*)&lt[lc * 72 + ch * 8];
        *(short8*)&ob[(size_t)(l0 + lc) * 256 + ci0 + ch * 8] = v;
    }
    if (blockIdx.x == 0 && t < 64)
        *(ob - 256 + ci0 + t) = 0;
    if (blockIdx.x == 63 && t < 128) {
        int r = 4096 + (t >> 6);
        ob[(size_t)r * 256 + ci0 + (t & 63)] = 0;
    }
}

// ---------------- bf16 blur + scale fold + optional guard rows (verified r16-r18) ---
__global__ __launch_bounds__(256) void blur_bf16_k(
    const ushort* __restrict__ in, int Lin,
    ushort* __restrict__ outp, int Lout,
    const float* __restrict__ scale,
    int pad, float c0, float c1, float c2, float c3,
    int gfront, int gback)
{
    int b = blockIdx.y;
    int idx = blockIdx.x * 256 + threadIdx.x;
    if (idx >= (gfront + Lout + gback) * 32) return;
    int row = (idx >> 5) - gfront;
    int ci = (idx & 31) * 8;
    ushort* ob = outp + (size_t)b * SRROW * 256;
    if (row < 0 || row >= Lout) {
        short8 z = {0, 0, 0, 0, 0, 0, 0, 0};
        *(short8*)(ob + (ptrdiff_t)row * 256 + ci) = z;
        return;
    }
    const ushort* ib = in + (size_t)b * SRROW * 256;
    float acc[8] = {};
    int base = row - pad;
    float cf[4] = {c0, c1, c2, c3};
    #pragma unroll
    for (int i = 0; i < 4; ++i) {
        int r = base + i;
        if (r >= 0 && r < Lin) {
            short8 v = *(const short8*)&ib[(size_t)r * 256 + ci];
            #pragma unroll
            for (int j = 0; j < 8; ++j) acc[j] += cf[i] * bf2f((ushort)v[j]);
        }
    }
    short8 o;
    #pragma unroll
    for (int j = 0; j < 8; ++j) {
        float sv = scale[b * CIN + ci + j];
        o[j] = (short)f2bf(acc[j] * sv);
    }
    *(short8*)&ob[(size_t)row * 256 + ci] = o;
}

// ======== conv same: 512 thr, 128co x 256l, BK=32, gload_lds (X-traffic halved) =======
// swizzle s(r) = (r>>1)&3 on 32-ci rows, both sides (verified r14)
__global__ __launch_bounds__(512, 4) void conv_same_mfma(
    const ushort* __restrict__ Tin, int Lmax,
    const ushort* __restrict__ Wl,              // [co][768]
    const float* __restrict__ dm, const float* __restrict__ post, float postScale,
    const float* __restrict__ bias,
    ushort* __restrict__ Tout, int guardL)
{
    __shared__ __align__(16) ushort S[20992];   // Xs 272x32 (8704) | Ws 384x32 (12288)
    ushort* Xs = S;
    ushort* Ws = S + 8704;
    int l0 = blockIdx.x * 256;
    int cot = blockIdx.y * 128;
    int b = blockIdx.z;
    int t = threadIdx.x;
    int lane = t & 63, wv = t >> 6;             // 8 waves
    int lr = lane & 15, lg = lane >> 4;         // lg 0..3 (4 x 8-ci slots)
    int srow = lane >> 2, sslot = lane & 3;     // staging: 16 rows x 4 slots per issue

    const ushort* Tb = Tin + (size_t)b * SRROW * 256;

    floatx4 acc[8][2];
    #pragma unroll
    for (int i = 0; i < 8; ++i) { acc[i][0] = (floatx4)0.f; acc[i][1] = (floatx4)0.f; }

    for (int ci0 = 0; ci0 < 256; ci0 += 32) {
        __syncthreads();
        for (int i = wv; i < 41; i += 8) {
            if (i < 17) {
                int ldr = i * 16 + srow;        // LDS X rows 0..271 (consume <=257)
                int dr = l0 - 1 + ldr;
                if (dr > Lmax) dr = Lmax;       // stay near data; clamped rows unconsumed
                gload16(Tb + (ptrdiff_t)dr * 256 + ci0 + ((sslot ^ ((ldr >> 1) & 3)) * 8),
                        Xs + i * 512);
            } else {
                int wr = (i - 17) * 16 + srow;  // W rows 0..383 = tap*128+co
                int co = wr & 127, tap = wr >> 7;
                gload16(Wl + (size_t)(cot + co) * 768 + tap * 256 + ci0 + ((sslot ^ ((wr >> 1) & 3)) * 8),
                        Ws + (i - 17) * 512);
            }
        }
        __syncthreads();
        #pragma unroll
        for (int tap = 0; tap < 3; ++tap) {
            short8 bf[2];
            #pragma unroll
            for (int nf = 0; nf < 2; ++nf) {
                int row = wv * 32 + nf * 16 + lr + tap;
                bf[nf] = *(const short8*)&Xs[row * 32 + ((lg ^ ((row >> 1) & 3)) * 8)];
            }
            #pragma unroll
            for (int mh = 0; mh < 2; ++mh) {
                short8 a[4];
                #pragma unroll
                for (int mf = 0; mf < 4; ++mf) {
                    int wr = tap * 128 + (mh * 4 + mf) * 16 + lr;
                    a[mf] = *(const short8*)&Ws[wr * 32 + ((lg ^ ((wr >> 1) & 3)) * 8)];
                }
                #pragma unroll
                for (int mf = 0; mf < 4; ++mf)
                    #pragma unroll
                    for (int nf = 0; nf < 2; ++nf)
                        acc[mh * 4 + mf][nf] =
                            __builtin_amdgcn_mfma_f32_16x16x32_bf16(a[mf], bf[nf], acc[mh * 4 + mf][nf], 0, 0, 0);
            }
        }
    }

    // epilogue: two 64-co halves through 256x72 transpose (pattern verified r10-r18)
    ushort* Ot = S;
    ushort* ob = Tout + (size_t)b * SRROW * 256;
    #pragma unroll
    for (int half = 0; half < 2; ++half) {
        __syncthreads();
        #pragma unroll
        for (int mf = 0; mf < 4; ++mf)
            #pragma unroll
            for (int nf = 0; nf < 2; ++nf)
                #pragma unroll
                for (int rg = 0; rg < 4; ++rg) {
                    int lo = wv * 32 + nf * 16 + lr;
                    int col = mf * 16 + lg * 4 + rg;          // 0..63 within half
                    int co = cot + half * 64 + col;
                    float dmv = dm[b * COUT + co] * KSCALE;
                    float v = acc[half * 4 + mf][nf][rg] * dmv + bias[co];
                    if (post) v *= post[b * COUT + co] * postScale;
                    Ot[lo * 72 + col] = f2bf(v);
                }
        __syncthreads();
        for (int idx = t; idx < 256 * 8; idx += 512) {
            int lo = idx >> 3, ch = idx & 7;
            short8 v = *(const short8*)&Ot[lo * 72 + ch * 8];
            *(short8*)&ob[(size_t)(l0 + lo) * 256 + cot + half * 64 + ch * 8] = v;
        }
    }
    // output guard rows (128-co slice)
    if (guardL > 0) {
        if (blockIdx.x == 0 && t < 128)
            *(ob - 256 + cot + t) = 0;
        if (l0 + 256 == guardL && t < 256) {
            int r = guardL + (t >> 7);
            ob[(size_t)r * 256 + cot + (t & 127)] = 0;
        }
    }
}

// ================= transpose conv stride 2: 512 thr, 64o x 256m (verified r11-r18) ====
__global__ __launch_bounds__(512, 4) void upconv_mfma(
    const ushort* __restrict__ Tin, int Lout,
    const ushort* __restrict__ Wl,      // [tap][o][c]
    const float* __restrict__ s, const float* __restrict__ bias,
    ushort* __restrict__ Tout)
{
    __shared__ __align__(16) ushort S[29184];   // Xs 264x64 | Ws 192x64
    ushort* Xs = S;
    ushort* Ws = S + 16896;
    int m0 = blockIdx.x * 256;
    int ot = blockIdx.y * 64;
    int b = blockIdx.z;
    int t = threadIdx.x;
    int lane = t & 63, wv = t >> 6;             // 8 waves
    int lr = lane & 15, lg = lane >> 4;
    int lrow = lane >> 3, cg = lane & 7;

    const ushort* Tb = Tin + (size_t)b * SRROW * 256;

    floatx4 aE[4][2], aO[4][2];
    #pragma unroll
    for (int i = 0; i < 4; ++i)
        #pragma unroll
        for (int j = 0; j < 2; ++j) { aE[i][j] = (floatx4)0.f; aO[i][j] = (floatx4)0.f; }

    for (int ci0 = 0; ci0 < 256; ci0 += 64) {
        __syncthreads();
        for (int i = wv; i < 24; i += 8) {
            int wr = i * 8 + lrow;
            int o = wr & 63, tap = wr >> 6;
            gload16(Wl + (size_t)tap * 65536 + (size_t)(ot + o) * 256 + ci0 + ((cg ^ (o & 7)) * 8),
                    Ws + i * 512);
        }
        for (int i = wv; i < 33; i += 8) {
            int row = i * 8 + lrow;
            gload16(Tb + (ptrdiff_t)(m0 - 1 + row) * 256 + ci0 + ((cg ^ (row & 7)) * 8),
                    Xs + i * 512);
        }
        __syncthreads();
        #pragma unroll
        for (int kk = 0; kk < 2; ++kk) {
            short8 bm1[2], bm[2];
            #pragma unroll
            for (int nf = 0; nf < 2; ++nf) {
                int r0 = wv * 32 + nf * 16 + lr;       // row r0 = x[m-1], r0+1 = x[m]
                int ci = kk * 32 + lg * 8;
                bm1[nf] = *(const short8*)&Xs[r0 * 64 + (ci ^ ((r0 & 7) * 8))];
                int r1 = r0 + 1;
                bm[nf]  = *(const short8*)&Xs[r1 * 64 + (ci ^ ((r1 & 7) * 8))];
            }
            #pragma unroll
            for (int tap = 0; tap < 3; ++tap) {
                short8 a[4];
                #pragma unroll
                for (int mf = 0; mf < 4; ++mf)
                    a[mf] = *(const short8*)&Ws[(tap * 64 + mf * 16 + lr) * 64 + ((kk * 32 + lg * 8) ^ ((lr & 7) * 8))];
                #pragma unroll
                for (int mf = 0; mf < 4; ++mf)
                    #pragma unroll
                    for (int nf = 0; nf < 2; ++nf) {
                        if (tap == 0) aE[mf][nf] = __builtin_amdgcn_mfma_f32_16x16x32_bf16(a[mf], bm[nf],  aE[mf][nf], 0, 0, 0);
                        if (tap == 2) aE[mf][nf] = __builtin_amdgcn_mfma_f32_16x16x32_bf16(a[mf], bm1[nf], aE[mf][nf], 0, 0, 0);
                        if (tap == 1) aO[mf][nf] = __builtin_amdgcn_mfma_f32_16x16x32_bf16(a[mf], bm[nf],  aO[mf][nf], 0, 0, 0);
                    }
            }
        }
    }

    // epilogue: two 256-row passes (waves 0-3 then 4-7), Ot = 256x72 (verified r11)
    ushort* Ot = S;
    ushort* ob = Tout + (size_t)b * SRROW * 256;
    __syncthreads();
    if (wv < 4) {
        #pragma unroll
        for (int mf = 0; mf < 4; ++mf)
            #pragma unroll
            for (int nf = 0; nf < 2; ++nf)
                #pragma unroll
                for (int rg = 0; rg < 4; ++rg) {
                    int mloc = wv * 32 + nf * 16 + lr;   // 0..127
                    int co = mf * 16 + lg * 4 + rg;
                    float sv = s[b * COUT + ot + co];
                    float bi = bias[ot + co];
                    Ot[(2 * mloc) * 72 + co]     = f2bf(aE[mf][nf][rg] * sv + bi);
                    Ot[(2 * mloc + 1) * 72 + co] = f2bf(aO[mf][nf][rg] * sv + bi);
                }
    }
    __syncthreads();
    for (int idx = t; idx < 256 * 8; idx += 512) {
        int lo = idx >> 3, ch = idx & 7;
        int n = 2 * m0 + lo;
        if (n < Lout) {
            short8 v = *(const short8*)&Ot[lo * 72 + ch * 8];
            *(short8*)&ob[(size_t)n * 256 + ot + ch * 8] = v;
        }
    }
    __syncthreads();
    if (wv >= 4) {
        #pragma unroll
        for (int mf = 0; mf < 4; ++mf)
            #pragma unroll
            for (int nf = 0; nf < 2; ++nf)
                #pragma unroll
                for (int rg = 0; rg < 4; ++rg) {
                    int mloc = wv * 32 + nf * 16 + lr;   // 128..255
                    int co = mf * 16 + lg * 4 + rg;
                    float sv = s[b * COUT + ot + co];
                    float bi = bias[ot + co];
                    Ot[(2 * mloc - 256) * 72 + co] = f2bf(aE[mf][nf][rg] * sv + bi);
                    Ot[(2 * mloc - 255) * 72 + co] = f2bf(aO[mf][nf][rg] * sv + bi);
                }
    }
    __syncthreads();
    for (int idx = t; idx < 256 * 8; idx += 512) {
        int lo = idx >> 3, ch = idx & 7;
        int n = 2 * m0 + 256 + lo;
        if (n < Lout) {
            short8 v = *(const short8*)&Ot[lo * 72 + ch * 8];
            *(short8*)&ob[(size_t)n * 256 + ot + ch * 8] = v;
        }
    }
}

// ======== stride-2 conv: 512 thr, 128co x 128l, BK=32 (X-traffic halved) ==============
__global__ __launch_bounds__(512, 4) void conv_down_mfma(
    const ushort* __restrict__ Tin,
    const ushort* __restrict__ Wl,      // [co][768]
    const float* __restrict__ dm, const float* __restrict__ bias,
    float* __restrict__ outp)
{
    __shared__ __align__(16) ushort S[20992];   // Xs 272x32 | Ws 384x32
    ushort* Xs = S;
    ushort* Ws = S + 8704;
    int l0 = blockIdx.x * 128;
    int cot = blockIdx.y * 128;
    int b = blockIdx.z;
    int t = threadIdx.x;
    int lane = t & 63, wv = t >> 6;             // wave owns l = l0 + wv*16 + lr
    int lr = lane & 15, lg = lane >> 4;
    int srow = lane >> 2, sslot = lane & 3;

    const ushort* Tb = Tin + (size_t)b * SRROW * 256;

    floatx4 acc[8];
    #pragma unroll
    for (int i = 0; i < 8; ++i) acc[i] = (floatx4)0.f;

    for (int ci0 = 0; ci0 < 256; ci0 += 32) {
        __syncthreads();
        for (int i = wv; i < 41; i += 8) {
            if (i < 17) {
                int ldr = i * 16 + srow;        // LDS X rows 0..271 (consume <=256)
                gload16(Tb + (ptrdiff_t)(2 * l0 + ldr) * 256 + ci0 + ((sslot ^ ((ldr >> 1) & 3)) * 8),
                        Xs + i * 512);
            } else {
                int wr = (i - 17) * 16 + srow;
                int co = wr & 127, tap = wr >> 7;
                gload16(Wl + (size_t)(cot + co) * 768 + tap * 256 + ci0 + ((sslot ^ ((wr >> 1) & 3)) * 8),
                        Ws + (i - 17) * 512);
            }
        }
        __syncthreads();
        #pragma unroll
        for (int tap = 0; tap < 3; ++tap) {
            int row = 2 * (wv * 16 + lr) + tap;
            short8 bf = *(const short8*)&Xs[row * 32 + ((lg ^ ((row >> 1) & 3)) * 8)];
            #pragma unroll
            for (int mh = 0; mh < 2; ++mh) {
                short8 a[4];
                #pragma unroll
                for (int mf = 0; mf < 4; ++mf) {
                    int wr = tap * 128 + (mh * 4 + mf) * 16 + lr;
                    a[mf] = *(const short8*)&Ws[wr * 32 + ((lg ^ ((wr >> 1) & 3)) * 8)];
                }
                #pragma unroll
                for (int mf = 0; mf < 4; ++mf)
                    acc[mh * 4 + mf] =
                        __builtin_amdgcn_mfma_f32_16x16x32_bf16(a[mf], bf, acc[mh * 4 + mf], 0, 0, 0);
            }
        }
    }

    float* ob = outp + (size_t)b * COUT * 4096;
    #pragma unroll
    for (int mf = 0; mf < 8; ++mf)
        #pragma unroll
        for (int rg = 0; rg < 4; ++rg) {
            int co = cot + mf * 16 + lg * 4 + rg;
            int l = l0 + wv * 16 + lr;
            float dmv = dm[b * COUT + co] * KSCALE;
            ob[(size_t)co * 4096 + l] = acc[mf][rg] * dmv + bias[co];
        }
}

extern "C" void kernel_launch(void* const* d_in, const int* in_sizes, int n_in,
                              void* d_out, int out_size, void* d_ws, size_t ws_size,
                              hipStream_t stream) {
    const float* x       = (const float*)d_in[0];
    const float* style   = (const float*)d_in[1];
    const float* weights = (const float*)d_in[2];
    const float* biases  = (const float*)d_in[3];
    const float* mod_w   = (const float*)d_in[4];
    const float* mod_b   = (const float*)d_in[5];
    float* out = (float*)d_out;

    float* s_all = (float*)d_ws;                       // 4*16*256
    float* demod_all = s_all + 4 * NB * CIN;           // 4*16*256
    const size_t WBF_OFF = 131072;                     // bytes
    const size_t BUF_OFF = WBF_OFF + 1572864;          // + Wbf (786432 ushorts)
    ushort* Wbf = (ushort*)((char*)d_ws + WBF_OFF);
    ushort* bufBase = (ushort*)((char*)d_ws + BUF_OFF);

    const int SL = NB * CIN;
    const size_t perSampleB = (size_t)2 * SRROW * 256 * sizeof(ushort);
    size_t availB = ws_size > BUF_OFF ? ws_size - BUF_OFF : 0;
    int g = (int)(availB / perSampleB);
    if (g < 1) g = 1;
    if (g > NB) g = NB;

    const size_t sElems = (size_t)SRROW * 256;
    ushort* bufAU = bufBase;
    ushort* bufBU = bufBase + (size_t)g * sElems;
    ushort* bufA = bufAU + 512;                        // data row 0 at underlying row 2
    ushort* bufB = bufBU + 512;

    // modulation + weight prep in ONE launch
    modwprep_k<<<1088, 256, 0, stream>>>(style, weights, mod_w, mod_b,
                                         s_all, demod_all, Wbf);

    for (int b0 = 0; b0 < NB; b0 += g) {
        int gb = NB - b0 < g ? NB - b0 : g;

        // T0 = bf16(x*s0) -> bufA (guards -1, 4096, 4097 folded in)
        xprep_k<<<dim3(64, 4, gb), 256, 0, stream>>>(
            x + (size_t)b0 * CIN * 4096, s_all + 0 * SL + b0 * CIN, bufA);

        // conv0 (same, L=4096, 128co tiles): bufA -> bufB = T1 (post = dm1*KSCALE)
        conv_same_mfma<<<dim3(16, 2, gb), 512, 0, stream>>>(
            bufA, 4097, Wbf + 0,
            demod_all + 0 * SL + b0 * CIN, demod_all + 1 * SL + b0 * CIN, KSCALE,
            biases + 0 * COUT, bufB, 4096);

        // upconv: bufB -> bufA = T2 (8193 data rows)
        upconv_mfma<<<dim3(17, 4, gb), 512, 0, stream>>>(
            bufB, 8193, Wbf + 196608,
            s_all + 1 * SL + b0 * CIN, biases + 1 * COUT, bufA);

        // blur1 (2*bk, pad 1), fold s2: T2(bufA) -> T3(bufB, 8192 rows + guards)
        blur_bf16_k<<<dim3(1025, gb), 256, 0, stream>>>(
            bufA, 8193, bufB, 8192, s_all + 2 * SL + b0 * CIN,
            1, 0.25f, 0.75f, 0.75f, 0.25f, 1, 2);

        // conv2 (same, L=8192, 128co tiles): T3(bufB) -> T4(bufA), no post
        conv_same_mfma<<<dim3(32, 2, gb), 512, 0, stream>>>(
            bufB, 8193, Wbf + 393216,
            demod_all + 2 * SL + b0 * CIN, (const float*)nullptr, 1.0f,
            biases + 2 * COUT, bufA, -1);

        // blur2 (bk, pad 2), fold s3: T4(bufA) -> T5(bufB, 8193 rows)
        blur_bf16_k<<<dim3(1025, gb), 256, 0, stream>>>(
            bufA, 8192, bufB, 8193, s_all + 3 * SL + b0 * CIN,
            2, 0.125f, 0.375f, 0.375f, 0.125f, 0, 0);

        // conv3 (down, 128co tiles): T5(bufB) -> out f32 [b][co][4096]
        conv_down_mfma<<<dim3(32, 2, gb), 512, 0, stream>>>(
            bufB, Wbf + 589824,
            demod_all + 3 * SL + b0 * CIN, biases + 3 * COUT,
            out + (size_t)b0 * COUT * 4096);
    }
}

// Round 20
// 297.391 us; speedup vs baseline: 1.0173x; 1.0173x over previous
//
#include <hip/hip_runtime.h>
#include <math.h>
#include <stddef.h>

#define CIN 256
#define COUT 256
#define SD 512
#define NB 16
#define KSCALE (1.0f / 48.0f)   // 1/sqrt(256*9)
#define MEPS 1e-8f
#define SRROW 8320               // per-sample row stride (rows of 256 bf16)

typedef __attribute__((ext_vector_type(8))) short short8;
typedef __attribute__((ext_vector_type(4))) float floatx4;
typedef unsigned short ushort;

__device__ inline ushort f2bf(float f) {
    union { float f; unsigned int u; } v; v.f = f;
    unsigned int u = v.u;
    return (ushort)((u + 0x7FFFu + ((u >> 16) & 1u)) >> 16);
}
__device__ inline float bf2f(ushort h) {
    union { unsigned int u; float f; } v; v.u = ((unsigned int)h) << 16;
    return v.f;
}

// async global->LDS, 16B per lane; LDS dest is wave-uniform base + lane*16
__device__ inline void gload16(const ushort* g, ushort* l) {
    __builtin_amdgcn_global_load_lds(
        (const __attribute__((address_space(1))) unsigned int*)g,
        (__attribute__((address_space(3))) unsigned int*)l,
        16, 0, 0);
}

// ---------------- modulation + weight prep, merged single launch (verified r18) -------
// blocks 0..63: mod (layer=blk>>4, b=blk&15); blocks 64..1087: wprep (4 x 256 blocks)
__global__ __launch_bounds__(256) void modwprep_k(
    const float* __restrict__ style, const float* __restrict__ weights,
    const float* __restrict__ mod_w, const float* __restrict__ mod_b,
    float* __restrict__ s_all, float* __restrict__ demod_all,
    ushort* __restrict__ Wbf)
{
    int t = threadIdx.x;
    if (blockIdx.x < 64) {
        int layer = blockIdx.x >> 4;
        int b = blockIdx.x & 15;
        __shared__ float st[SD];
        __shared__ float s2[CIN];

        for (int j = t; j < SD; j += 256) st[j] = style[b * SD + j];
        __syncthreads();

        const float* mw = mod_w + ((size_t)layer * CIN + t) * SD;
        float acc = 0.f;
        for (int j = 0; j < SD; ++j) acc += mw[j] * st[j];
        float s = acc + mod_b[layer * CIN + t];
        s_all[((size_t)layer * NB + b) * CIN + t] = s;
        s2[t] = s * s;
        __syncthreads();

        const float* wr = weights + ((size_t)layer * COUT + t) * (CIN * 3);
        float d = 0.f;
        for (int ci = 0; ci < CIN; ++ci) {
            float w0 = wr[ci * 3 + 0], w1 = wr[ci * 3 + 1], w2 = wr[ci * 3 + 2];
            d += (w0 * w0 + w1 * w1 + w2 * w2) * s2[ci];
        }
        demod_all[((size_t)layer * NB + b) * CIN + t] = rsqrtf(KSCALE * KSCALE * d + MEPS);
    } else {
        int lin = blockIdx.x - 64;
        int layer = lin >> 8;                 // 256 blocks per layer
        int idx = (lin & 255) * 256 + t;      // 0..65535
        int a = idx >> 8, c = idx & 255;
        ushort* wl = Wbf + (size_t)layer * 196608;
        if (layer == 1) {
            const float* src = weights + ((size_t)1 * 196608) + ((size_t)c * 256 + a) * 3;
            #pragma unroll
            for (int k = 0; k < 3; ++k)
                wl[(size_t)k * 65536 + a * 256 + c] = f2bf(src[k]);
        } else {
            const float* src = weights + ((size_t)layer * 196608) + ((size_t)a * 256 + c) * 3;
            #pragma unroll
            for (int k = 0; k < 3; ++k)
                wl[(size_t)a * 768 + k * 256 + c] = f2bf(src[k]);
        }
    }
}

// ---------------- x prep + T0 guard rows (verified r16-r18) ----------------
__global__ __launch_bounds__(256) void xprep_k(
    const float* __restrict__ x, const float* __restrict__ s0,
    ushort* __restrict__ Tout)
{
    __shared__ ushort lt[64 * 72];
    int l0 = blockIdx.x * 64, ci0 = blockIdx.y * 64;
    int b = blockIdx.z;
    int t = threadIdx.x;
    const float* xb = x + (size_t)b * CIN * 4096;
    const float* sb = s0 + b * CIN;

    for (int idx = t; idx < 64 * 64; idx += 256) {
        int ci = idx >> 6, lc = idx & 63;
        float v = xb[(size_t)(ci0 + ci) * 4096 + l0 + lc] * sb[ci0 + ci];
        lt[lc * 72 + ci] = f2bf(v);
    }
    __syncthreads();
    ushort* ob = Tout + (size_t)b * SRROW * 256;
    for (int idx = t; idx < 64 * 8; idx += 256) {
        int lc = idx >> 3, ch = idx & 7;
        short8 v = *(const short8*)&lt[lc * 72 + ch * 8];
        *(short8*)&ob[(size_t)(l0 + lc) * 256 + ci0 + ch * 8] = v;
    }
    // guards: data row -1 (front) and 4096,4097 (tail), this block's ci slice
    if (blockIdx.x == 0 && t < 64)
        *(ob - 256 + ci0 + t) = 0;
    if (blockIdx.x == 63 && t < 128) {
        int r = 4096 + (t >> 6);
        ob[(size_t)r * 256 + ci0 + (t & 63)] = 0;
    }
}

// ---------------- bf16 blur (channel-last) + scale fold + optional guard rows ---
__global__ __launch_bounds__(256) void blur_bf16_k(
    const ushort* __restrict__ in, int Lin,
    ushort* __restrict__ outp, int Lout,
    const float* __restrict__ scale,   // [b][256]
    int pad, float c0, float c1, float c2, float c3,
    int gfront, int gback)
{
    int b = blockIdx.y;
    int idx = blockIdx.x * 256 + threadIdx.x;
    if (idx >= (gfront + Lout + gback) * 32) return;
    int row = (idx >> 5) - gfront;
    int ci = (idx & 31) * 8;
    ushort* ob = outp + (size_t)b * SRROW * 256;
    if (row < 0 || row >= Lout) {
        short8 z = {0, 0, 0, 0, 0, 0, 0, 0};
        *(short8*)(ob + (ptrdiff_t)row * 256 + ci) = z;
        return;
    }
    const ushort* ib = in + (size_t)b * SRROW * 256;
    float acc[8] = {};
    int base = row - pad;
    float cf[4] = {c0, c1, c2, c3};
    #pragma unroll
    for (int i = 0; i < 4; ++i) {
        int r = base + i;
        if (r >= 0 && r < Lin) {
            short8 v = *(const short8*)&ib[(size_t)r * 256 + ci];
            #pragma unroll
            for (int j = 0; j < 8; ++j) acc[j] += cf[i] * bf2f((ushort)v[j]);
        }
    }
    short8 o;
    #pragma unroll
    for (int j = 0; j < 8; ++j) {
        float sv = scale[b * CIN + ci + j];
        o[j] = (short)f2bf(acc[j] * sv);
    }
    *(short8*)&ob[(size_t)row * 256 + ci] = o;
}

// ================= conv same: 512 thr, 64co x 256l, gload_lds (verified r10-r18) ======
// out = bf16( (acc*dm*KSCALE + bias) * (post ? post*postScale : 1) )
// guardL>0: blocks x==0 / last also zero output guard rows {-1} / {guardL, guardL+1}
__global__ __launch_bounds__(512, 4) void conv_same_mfma(
    const ushort* __restrict__ Tin, int Lmax,   // data-coord clamp for staging
    const ushort* __restrict__ Wl,              // [co][768]
    const float* __restrict__ dm, const float* __restrict__ post, float postScale,
    const float* __restrict__ bias,
    ushort* __restrict__ Tout, int guardL)
{
    __shared__ __align__(16) ushort S[29184];   // Xs 264x64 (16896) | Ws 192x64 (12288)
    ushort* Xs = S;
    ushort* Ws = S + 16896;
    int l0 = blockIdx.x * 256;
    int cot = blockIdx.y * 64;
    int b = blockIdx.z;
    int t = threadIdx.x;
    int lane = t & 63, wv = t >> 6;             // 8 waves
    int lr = lane & 15, lg = lane >> 4;
    int lrow = lane >> 3, cg = lane & 7;

    const ushort* Tb = Tin + (size_t)b * SRROW * 256;

    floatx4 acc[4][2];
    #pragma unroll
    for (int i = 0; i < 4; ++i) { acc[i][0] = (floatx4)0.f; acc[i][1] = (floatx4)0.f; }

    for (int ci0 = 0; ci0 < 256; ci0 += 64) {
        __syncthreads();
        for (int i = wv; i < 24; i += 8) {
            int wr = i * 8 + lrow;
            int co = wr & 63, tap = wr >> 6;
            gload16(Wl + (size_t)(cot + co) * 768 + tap * 256 + ci0 + ((cg ^ (co & 7)) * 8),
                    Ws + i * 512);
        }
        for (int i = wv; i < 33; i += 8) {
            int row = i * 8 + lrow;
            int dr = l0 - 1 + row;
            if (dr > Lmax) dr = Lmax;           // stay near data; clamped rows unconsumed
            gload16(Tb + (ptrdiff_t)dr * 256 + ci0 + ((cg ^ (row & 7)) * 8),
                    Xs + i * 512);
        }
        __syncthreads();
        #pragma unroll
        for (int tap = 0; tap < 3; ++tap)
            #pragma unroll
            for (int kk = 0; kk < 2; ++kk) {
                short8 a[4];
                #pragma unroll
                for (int mf = 0; mf < 4; ++mf)
                    a[mf] = *(const short8*)&Ws[(tap * 64 + mf * 16 + lr) * 64 + ((kk * 32 + lg * 8) ^ ((lr & 7) * 8))];
                short8 bf[2];
                #pragma unroll
                for (int nf = 0; nf < 2; ++nf) {
                    int row = wv * 32 + nf * 16 + lr + tap;
                    bf[nf] = *(const short8*)&Xs[row * 64 + ((kk * 32 + lg * 8) ^ ((row & 7) * 8))];
                }
                #pragma unroll
                for (int mf = 0; mf < 4; ++mf)
                    #pragma unroll
                    for (int nf = 0; nf < 2; ++nf)
                        acc[mf][nf] = __builtin_amdgcn_mfma_f32_16x16x32_bf16(a[mf], bf[nf], acc[mf][nf], 0, 0, 0);
            }
    }

    __syncthreads();
    ushort* Ot = S;   // 256 x 72
    #pragma unroll
    for (int mf = 0; mf < 4; ++mf)
        #pragma unroll
        for (int nf = 0; nf < 2; ++nf)
            #pragma unroll
            for (int rg = 0; rg < 4; ++rg) {
                int lo = wv * 32 + nf * 16 + lr;
                int co = mf * 16 + lg * 4 + rg;
                float dmv = dm[b * COUT + cot + co] * KSCALE;
                float v = acc[mf][nf][rg] * dmv + bias[cot + co];
                if (post) v *= post[b * COUT + cot + co] * postScale;
                Ot[lo * 72 + co] = f2bf(v);
            }
    __syncthreads();
    ushort* ob = Tout + (size_t)b * SRROW * 256;
    for (int idx = t; idx < 256 * 8; idx += 512) {
        int lo = idx >> 3, ch = idx & 7;
        short8 v = *(const short8*)&Ot[lo * 72 + ch * 8];
        *(short8*)&ob[(size_t)(l0 + lo) * 256 + cot + ch * 8] = v;
    }
    // output guard rows (fold of guard_k): this block's 64-co slice
    if (guardL > 0) {
        if (blockIdx.x == 0 && t < 64)
            *(ob - 256 + cot + t) = 0;
        if (l0 + 256 == guardL && t < 128) {
            int r = guardL + (t >> 6);
            ob[(size_t)r * 256 + cot + (t & 63)] = 0;
        }
    }
}

// ================= transpose conv stride 2: 512 thr, 64o x 256m (verified r11-r18) ====
__global__ __launch_bounds__(512, 4) void upconv_mfma(
    const ushort* __restrict__ Tin, int Lout,
    const ushort* __restrict__ Wl,      // [tap][o][c]
    const float* __restrict__ s, const float* __restrict__ bias,
    ushort* __restrict__ Tout)
{
    __shared__ __align__(16) ushort S[29184];   // Xs 264x64 | Ws 192x64
    ushort* Xs = S;
    ushort* Ws = S + 16896;
    int m0 = blockIdx.x * 256;
    int ot = blockIdx.y * 64;
    int b = blockIdx.z;
    int t = threadIdx.x;
    int lane = t & 63, wv = t >> 6;             // 8 waves
    int lr = lane & 15, lg = lane >> 4;
    int lrow = lane >> 3, cg = lane & 7;

    const ushort* Tb = Tin + (size_t)b * SRROW * 256;

    floatx4 aE[4][2], aO[4][2];
    #pragma unroll
    for (int i = 0; i < 4; ++i)
        #pragma unroll
        for (int j = 0; j < 2; ++j) { aE[i][j] = (floatx4)0.f; aO[i][j] = (floatx4)0.f; }

    for (int ci0 = 0; ci0 < 256; ci0 += 64) {
        __syncthreads();
        for (int i = wv; i < 24; i += 8) {
            int wr = i * 8 + lrow;
            int o = wr & 63, tap = wr >> 6;
            gload16(Wl + (size_t)tap * 65536 + (size_t)(ot + o) * 256 + ci0 + ((cg ^ (o & 7)) * 8),
                    Ws + i * 512);
        }
        for (int i = wv; i < 33; i += 8) {
            int row = i * 8 + lrow;
            gload16(Tb + (ptrdiff_t)(m0 - 1 + row) * 256 + ci0 + ((cg ^ (row & 7)) * 8),
                    Xs + i * 512);
        }
        __syncthreads();
        #pragma unroll
        for (int kk = 0; kk < 2; ++kk) {
            short8 bm1[2], bm[2];
            #pragma unroll
            for (int nf = 0; nf < 2; ++nf) {
                int r0 = wv * 32 + nf * 16 + lr;       // row r0 = x[m-1], r0+1 = x[m]
                int ci = kk * 32 + lg * 8;
                bm1[nf] = *(const short8*)&Xs[r0 * 64 + (ci ^ ((r0 & 7) * 8))];
                int r1 = r0 + 1;
                bm[nf]  = *(const short8*)&Xs[r1 * 64 + (ci ^ ((r1 & 7) * 8))];
            }
            #pragma unroll
            for (int tap = 0; tap < 3; ++tap) {
                short8 a[4];
                #pragma unroll
                for (int mf = 0; mf < 4; ++mf)
                    a[mf] = *(const short8*)&Ws[(tap * 64 + mf * 16 + lr) * 64 + ((kk * 32 + lg * 8) ^ ((lr & 7) * 8))];
                #pragma unroll
                for (int mf = 0; mf < 4; ++mf)
                    #pragma unroll
                    for (int nf = 0; nf < 2; ++nf) {
                        if (tap == 0) aE[mf][nf] = __builtin_amdgcn_mfma_f32_16x16x32_bf16(a[mf], bm[nf],  aE[mf][nf], 0, 0, 0);
                        if (tap == 2) aE[mf][nf] = __builtin_amdgcn_mfma_f32_16x16x32_bf16(a[mf], bm1[nf], aE[mf][nf], 0, 0, 0);
                        if (tap == 1) aO[mf][nf] = __builtin_amdgcn_mfma_f32_16x16x32_bf16(a[mf], bm[nf],  aO[mf][nf], 0, 0, 0);
                    }
            }
        }
    }

    // epilogue: two 256-row passes (waves 0-3 then 4-7), Ot = 256x72 (verified r11)
    ushort* Ot = S;
    ushort* ob = Tout + (size_t)b * SRROW * 256;
    __syncthreads();
    if (wv < 4) {
        #pragma unroll
        for (int mf = 0; mf < 4; ++mf)
            #pragma unroll
            for (int nf = 0; nf < 2; ++nf)
                #pragma unroll
                for (int rg = 0; rg < 4; ++rg) {
                    int mloc = wv * 32 + nf * 16 + lr;   // 0..127
                    int co = mf * 16 + lg * 4 + rg;
                    float sv = s[b * COUT + ot + co];
                    float bi = bias[ot + co];
                    Ot[(2 * mloc) * 72 + co]     = f2bf(aE[mf][nf][rg] * sv + bi);
                    Ot[(2 * mloc + 1) * 72 + co] = f2bf(aO[mf][nf][rg] * sv + bi);
                }
    }
    __syncthreads();
    for (int idx = t; idx < 256 * 8; idx += 512) {
        int lo = idx >> 3, ch = idx & 7;
        int n = 2 * m0 + lo;
        if (n < Lout) {
            short8 v = *(const short8*)&Ot[lo * 72 + ch * 8];
            *(short8*)&ob[(size_t)n * 256 + ot + ch * 8] = v;
        }
    }
    __syncthreads();
    if (wv >= 4) {
        #pragma unroll
        for (int mf = 0; mf < 4; ++mf)
            #pragma unroll
            for (int nf = 0; nf < 2; ++nf)
                #pragma unroll
                for (int rg = 0; rg < 4; ++rg) {
                    int mloc = wv * 32 + nf * 16 + lr;   // 128..255
                    int co = mf * 16 + lg * 4 + rg;
                    float sv = s[b * COUT + ot + co];
                    float bi = bias[ot + co];
                    Ot[(2 * mloc - 256) * 72 + co] = f2bf(aE[mf][nf][rg] * sv + bi);
                    Ot[(2 * mloc - 255) * 72 + co] = f2bf(aO[mf][nf][rg] * sv + bi);
                }
    }
    __syncthreads();
    for (int idx = t; idx < 256 * 8; idx += 512) {
        int lo = idx >> 3, ch = idx & 7;
        int n = 2 * m0 + 256 + lo;
        if (n < Lout) {
            short8 v = *(const short8*)&Ot[lo * 72 + ch * 8];
            *(short8*)&ob[(size_t)n * 256 + ot + ch * 8] = v;
        }
    }
}

// ================= stride-2 conv: 512 thr, 64co x 128l, gload_lds (verified r11-r18) ===
__global__ __launch_bounds__(512, 4) void conv_down_mfma(
    const ushort* __restrict__ Tin,
    const ushort* __restrict__ Wl,      // [co][768]
    const float* __restrict__ dm, const float* __restrict__ bias,
    float* __restrict__ outp)
{
    __shared__ __align__(16) ushort S[29184];   // Xs 264x64 | Ws 192x64
    ushort* Xs = S;
    ushort* Ws = S + 16896;
    int l0 = blockIdx.x * 128;
    int cot = blockIdx.y * 64;
    int b = blockIdx.z;
    int t = threadIdx.x;
    int lane = t & 63, wv = t >> 6;             // wave owns l = l0 + wv*16 + lr
    int lr = lane & 15, lg = lane >> 4;
    int lrow = lane >> 3, cg = lane & 7;

    const ushort* Tb = Tin + (size_t)b * SRROW * 256;

    floatx4 acc[4];
    #pragma unroll
    for (int i = 0; i < 4; ++i) acc[i] = (floatx4)0.f;

    for (int ci0 = 0; ci0 < 256; ci0 += 64) {
        __syncthreads();
        for (int i = wv; i < 24; i += 8) {
            int wr = i * 8 + lrow;
            int co = wr & 63, tap = wr >> 6;
            gload16(Wl + (size_t)(cot + co) * 768 + tap * 256 + ci0 + ((cg ^ (co & 7)) * 8),
                    Ws + i * 512);
        }
        for (int i = wv; i < 33; i += 8) {
            int row = i * 8 + lrow;
            gload16(Tb + (ptrdiff_t)(2 * l0 + row) * 256 + ci0 + ((cg ^ (row & 7)) * 8),
                    Xs + i * 512);
        }
        __syncthreads();
        #pragma unroll
        for (int tap = 0; tap < 3; ++tap)
            #pragma unroll
            for (int kk = 0; kk < 2; ++kk) {
                short8 a[4];
                #pragma unroll
                for (int mf = 0; mf < 4; ++mf)
                    a[mf] = *(const short8*)&Ws[(tap * 64 + mf * 16 + lr) * 64 + ((kk * 32 + lg * 8) ^ ((lr & 7) * 8))];
                int row = 2 * (wv * 16 + lr) + tap;
                short8 bf = *(const short8*)&Xs[row * 64 + ((kk * 32 + lg * 8) ^ ((row & 7) * 8))];
                #pragma unroll
                for (int mf = 0; mf < 4; ++mf)
                    acc[mf] = __builtin_amdgcn_mfma_f32_16x16x32_bf16(a[mf], bf, acc[mf], 0, 0, 0);
            }
    }

    float* ob = outp + (size_t)b * COUT * 4096;
    #pragma unroll
    for (int mf = 0; mf < 4; ++mf)
        #pragma unroll
        for (int rg = 0; rg < 4; ++rg) {
            int co = cot + mf * 16 + lg * 4 + rg;
            int l = l0 + wv * 16 + lr;
            float dmv = dm[b * COUT + co] * KSCALE;
            ob[(size_t)co * 4096 + l] = acc[mf][rg] * dmv + bias[co];
        }
}

extern "C" void kernel_launch(void* const* d_in, const int* in_sizes, int n_in,
                              void* d_out, int out_size, void* d_ws, size_t ws_size,
                              hipStream_t stream) {
    const float* x       = (const float*)d_in[0];
    const float* style   = (const float*)d_in[1];
    const float* weights = (const float*)d_in[2];
    const float* biases  = (const float*)d_in[3];
    const float* mod_w   = (const float*)d_in[4];
    const float* mod_b   = (const float*)d_in[5];
    float* out = (float*)d_out;

    float* s_all = (float*)d_ws;                       // 4*16*256
    float* demod_all = s_all + 4 * NB * CIN;           // 4*16*256
    const size_t WBF_OFF = 131072;                     // bytes
    const size_t BUF_OFF = WBF_OFF + 1572864;          // + Wbf (786432 ushorts)
    ushort* Wbf = (ushort*)((char*)d_ws + WBF_OFF);
    ushort* bufBase = (ushort*)((char*)d_ws + BUF_OFF);

    const int SL = NB * CIN;
    const size_t perSampleB = (size_t)2 * SRROW * 256 * sizeof(ushort);
    size_t availB = ws_size > BUF_OFF ? ws_size - BUF_OFF : 0;
    int g = (int)(availB / perSampleB);
    if (g < 1) g = 1;
    if (g > NB) g = NB;

    const size_t sElems = (size_t)SRROW * 256;
    ushort* bufAU = bufBase;
    ushort* bufBU = bufBase + (size_t)g * sElems;
    ushort* bufA = bufAU + 512;                        // data row 0 at underlying row 2
    ushort* bufB = bufBU + 512;

    // modulation + weight prep in ONE launch (mod: blocks 0..63; wprep: 64..1087)
    modwprep_k<<<1088, 256, 0, stream>>>(style, weights, mod_w, mod_b,
                                         s_all, demod_all, Wbf);

    for (int b0 = 0; b0 < NB; b0 += g) {
        int gb = NB - b0 < g ? NB - b0 : g;

        // T0 = bf16(x*s0) -> bufA (guards -1, 4096, 4097 folded in)
        xprep_k<<<dim3(64, 4, gb), 256, 0, stream>>>(
            x + (size_t)b0 * CIN * 4096, s_all + 0 * SL + b0 * CIN, bufA);

        // conv0 (same, L=4096): bufA -> bufB = T1 (post = dm1*KSCALE; guards folded)
        conv_same_mfma<<<dim3(16, 4, gb), 512, 0, stream>>>(
            bufA, 4097, Wbf + 0,
            demod_all + 0 * SL + b0 * CIN, demod_all + 1 * SL + b0 * CIN, KSCALE,
            biases + 0 * COUT, bufB, 4096);

        // upconv: bufB -> bufA = T2 (8193 data rows)
        upconv_mfma<<<dim3(17, 4, gb), 512, 0, stream>>>(
            bufB, 8193, Wbf + 196608,
            s_all + 1 * SL + b0 * CIN, biases + 1 * COUT, bufA);

        // blur1 (2*bk, pad 1), fold s2: T2(bufA) -> T3(bufB, 8192 rows + guards -1,8192,8193)
        blur_bf16_k<<<dim3(1025, gb), 256, 0, stream>>>(
            bufA, 8193, bufB, 8192, s_all + 2 * SL + b0 * CIN,
            1, 0.25f, 0.75f, 0.75f, 0.25f, 1, 2);

        // conv2 (same, L=8192): T3(bufB) -> T4(bufA), no post, no output guards
        conv_same_mfma<<<dim3(32, 4, gb), 512, 0, stream>>>(
            bufB, 8193, Wbf + 393216,
            demod_all + 2 * SL + b0 * CIN, (const float*)nullptr, 1.0f,
            biases + 2 * COUT, bufA, -1);

        // blur2 (bk, pad 2), fold s3: T4(bufA) -> T5(bufB, 8193 rows, no guards needed)
        blur_bf16_k<<<dim3(1025, gb), 256, 0, stream>>>(
            bufA, 8192, bufB, 8193, s_all + 3 * SL + b0 * CIN,
            2, 0.125f, 0.375f, 0.375f, 0.125f, 0, 0);

        // conv3 (down): T5(bufB) -> out f32 [b][co][4096]
        conv_down_mfma<<<dim3(32, 4, gb), 512, 0, stream>>>(
            bufB, Wbf + 589824,
            demod_all + 3 * SL + b0 * CIN, biases + 3 * COUT,
            out + (size_t)b0 * COUT * 4096);
    }
}